// Round 1
// baseline (892.462 us; speedup 1.0000x reference)
//
#include <hip/hip_runtime.h>
#include <hip/hip_bf16.h>
#include <stdint.h>

#define AS1 __attribute__((address_space(1)))
#define AS3 __attribute__((address_space(3)))

typedef __bf16 bf16_t;
typedef bf16_t bf16x8 __attribute__((ext_vector_type(8)));
typedef float f32x4 __attribute__((ext_vector_type(4)));
typedef unsigned short u16;
typedef u16 u16x4 __attribute__((ext_vector_type(4)));

#define MFMA16(a, b, c) __builtin_amdgcn_mfma_f32_16x16x32_bf16(a, b, c, 0, 0, 0)

static __device__ __forceinline__ void gload_lds16(const void* g, void* l) {
    __builtin_amdgcn_global_load_lds((const AS1 void*)g, (AS3 void*)l, 16, 0, 0);
}

// Stage 16KB tile into LDS with XOR swizzle ((row&7)<<4) applied on the GLOBAL
// source address (global_load_lds writes LDS linearly: wave base + lane*16).
// ROW_SHIFT = log2(row bytes): 7 -> 128B rows (128 rows), 8 -> 256B rows (64 rows).
template <int ROW_SHIFT>
static __device__ __forceinline__ void stage16k(const char* g, char* lds, int gstride, int tid) {
    const int lane = tid & 63, w = tid >> 6;
#pragma unroll
    for (int i = 0; i < 4; ++i) {
        int chunk = w + i * 4;  // wave-uniform
        int p = chunk * 1024 + lane * 16;
        int row = p >> ROW_SHIFT;
        int col = (p & ((1 << ROW_SHIFT) - 1)) ^ ((row & 7) << 4);
        gload_lds16(g + row * gstride + col, lds + chunk * 1024);
    }
}

template <int ROW_SHIFT>
static __device__ __forceinline__ bf16x8 lds_frag(const char* lds, int row, int colb) {
    int off = (row << ROW_SHIFT) + (colb ^ ((row & 7) << 4));
    return *(const bf16x8*)(lds + off);
}

// ---------------------------------------------------------------- pack f32->bf16
__global__ __launch_bounds__(256) void pack_bf16(
    const float* q, const float* k, const float* v,
    const float* wq, const float* wk, const float* wv, const float* wo,
    bf16_t* qb, bf16_t* kb, bf16_t* vb,
    bf16_t* wqb, bf16_t* wkb, bf16_t* wvb, bf16_t* wob) {
    const float* src; bf16_t* dst; int n;
    switch (blockIdx.y) {
        case 0: src = q;  dst = qb;  n = 4194304; break;
        case 1: src = k;  dst = kb;  n = 4194304; break;
        case 2: src = v;  dst = vb;  n = 4194304; break;
        case 3: src = wq; dst = wqb; n = 1048576; break;
        case 4: src = wk; dst = wkb; n = 1048576; break;
        case 5: src = wv; dst = wvb; n = 1048576; break;
        default: src = wo; dst = wob; n = 1048576; break;
    }
    int i = (blockIdx.x * 256 + threadIdx.x) * 8;
    if (i >= n) return;
    f32x4 v0 = *(const f32x4*)(src + i);
    f32x4 v1 = *(const f32x4*)(src + i + 4);
    bf16x8 o;
#pragma unroll
    for (int e = 0; e < 4; ++e) o[e] = (bf16_t)v0[e];
#pragma unroll
    for (int e = 0; e < 4; ++e) o[e + 4] = (bf16_t)v1[e];
    *(bf16x8*)(dst + i) = o;
}

// ---------------------------------------------------------------- NT GEMM (bf16 MFMA)
// C[M=4096, N=1024] = A[M,K=1024] * B[N,K]^T + bias
// MODE 0: z in {0,1,2} selects q/k/v; epilogue -> split-head bf16 (z=0 Qs, z=1 Ks) or
//         transposed-per-head bf16 Vt (z=2).
// MODE 1: epilogue -> f32 out (d_out).
template <int MODE>
__global__ __launch_bounds__(256, 2) void gemm_nt(
    const bf16_t* A0, const bf16_t* A1, const bf16_t* A2,
    const bf16_t* B0, const bf16_t* B1, const bf16_t* B2,
    const float* bias0, const float* bias1, const float* bias2,
    bf16_t* Qs, bf16_t* Ks, bf16_t* Vt, float* outF) {
    __shared__ __align__(1024) char sm[32768];
    const int tid = threadIdx.x, lane = tid & 63, w = tid >> 6;
    const int wr = w >> 1, wc = w & 1;
    const int m0 = blockIdx.y * 128, n0 = blockIdx.x * 128;
    const int z = (MODE == 0) ? blockIdx.z : 0;

    const bf16_t* A; const bf16_t* Bw; const float* bias;
    if (MODE == 0) {
        A    = (z == 0) ? A0 : (z == 1) ? A1 : A2;
        Bw   = (z == 0) ? B0 : (z == 1) ? B1 : B2;
        bias = (z == 0) ? bias0 : (z == 1) ? bias1 : bias2;
    } else { A = A0; Bw = B0; bias = bias0; }

    const char* Ab = (const char*)A + (size_t)m0 * 2048;
    const char* Bb = (const char*)Bw + (size_t)n0 * 2048;

    f32x4 acc[4][4] = {};
    for (int k0 = 0; k0 < 1024; k0 += 64) {
        stage16k<7>(Ab + k0 * 2, sm, 2048, tid);
        stage16k<7>(Bb + k0 * 2, sm + 16384, 2048, tid);
        __syncthreads();
#pragma unroll
        for (int kk = 0; kk < 2; ++kk) {
            bf16x8 af[4], bfr[4];
#pragma unroll
            for (int i = 0; i < 4; ++i)
                af[i] = lds_frag<7>(sm, wr * 64 + i * 16 + (lane & 15), kk * 64 + (lane >> 4) * 16);
#pragma unroll
            for (int j = 0; j < 4; ++j)
                bfr[j] = lds_frag<7>(sm + 16384, wc * 64 + j * 16 + (lane & 15), kk * 64 + (lane >> 4) * 16);
#pragma unroll
            for (int i = 0; i < 4; ++i)
#pragma unroll
                for (int j = 0; j < 4; ++j)
                    acc[i][j] = MFMA16(af[i], bfr[j], acc[i][j]);
        }
        __syncthreads();
    }

#pragma unroll
    for (int i = 0; i < 4; ++i) {
#pragma unroll
        for (int j = 0; j < 4; ++j) {
            const int mb = m0 + wr * 64 + i * 16 + ((lane >> 4) << 2);
            const int n = n0 + wc * 64 + j * 16 + (lane & 15);
            const float bv = bias[n];
            if (MODE == 1) {
#pragma unroll
                for (int r = 0; r < 4; ++r)
                    outF[(size_t)(mb + r) * 1024 + n] = acc[i][j][r] + bv;
            } else if (z == 2) {
                const int b = mb >> 10, l = mb & 1023;
                const int h = n >> 6, d = n & 63;
                u16x4 pk;
#pragma unroll
                for (int r = 0; r < 4; ++r) {
                    bf16_t x = (bf16_t)(acc[i][j][r] + bv);
                    pk[r] = __builtin_bit_cast(u16, x);
                }
                *(u16x4*)&Vt[((size_t)((b * 16 + h) * 64 + d)) * 1024 + l] = pk;
            } else {
                bf16_t* dst = (z == 0) ? Qs : Ks;
                const int h = n >> 6, d = n & 63;
#pragma unroll
                for (int r = 0; r < 4; ++r) {
                    const int m = mb + r, b = m >> 10, l = m & 1023;
                    dst[((size_t)((b * 16 + h) * 1024 + l)) * 64 + d] = (bf16_t)(acc[i][j][r] + bv);
                }
            }
        }
    }
}

// ---------------------------------------------------------------- scores + stats
// Per block: one (bh, 128-row q tile). 4 waves, each owns 32 q rows.
// S = Q K^T (MFMA, K=64); blended = g*prev + (1-g)*S -> scoresOut (d_out region).
// Online masked (k < len), /8 row max & sum-exp -> rowMax/rowSum.
__global__ __launch_bounds__(256, 2) void attn_scores(
    const bf16_t* Qs, const bf16_t* Ks,
    const float* prev, const int* mask, const float* gatp,
    float* scoresOut, float* rowMax, float* rowSum) {
    __shared__ __align__(1024) char sm[16384];
    const int tid = threadIdx.x, lane = tid & 63, w = tid >> 6;
    const int bh = blockIdx.y;
    const int q0 = blockIdx.x * 128 + w * 32;
    const float gv = gatp[0];
    const float g = 1.f / (1.f + __expf(-gv));
    const float og = 1.f - g;

    // A-frags (A layout: row = lane&15, k = (lane>>4)*8 + e)
    bf16x8 qa[2][2];
#pragma unroll
    for (int mi = 0; mi < 2; ++mi)
#pragma unroll
        for (int kk = 0; kk < 2; ++kk) {
            const int q = q0 + mi * 16 + (lane & 15);
            qa[mi][kk] = *(const bf16x8*)(Qs + ((size_t)(bh * 1024 + q)) * 64 + kk * 32 + (lane >> 4) * 8);
        }
    // per-row state (C layout rows: (lane>>4)*4 + r)
    int lenv[2][4];
    float mrun[2][4], lrun[2][4];
#pragma unroll
    for (int mi = 0; mi < 2; ++mi)
#pragma unroll
        for (int r = 0; r < 4; ++r) {
            const int q = q0 + mi * 16 + ((lane >> 4) << 2) + r;
            lenv[mi][r] = mask[(bh & 3) * 1024 + q];
            mrun[mi][r] = -1e30f;
            lrun[mi][r] = 0.f;
        }

    const char* Kb = (const char*)Ks + (size_t)bh * 131072;  // 1024*64*2B
    for (int kt = 0; kt < 8; ++kt) {
        stage16k<7>(Kb + kt * 16384, sm, 128, tid);
        __syncthreads();
        f32x4 s[2][8] = {};
#pragma unroll
        for (int kk = 0; kk < 2; ++kk) {
            bf16x8 bfr[8];
#pragma unroll
            for (int j = 0; j < 8; ++j)
                bfr[j] = lds_frag<7>(sm, j * 16 + (lane & 15), kk * 64 + (lane >> 4) * 16);
#pragma unroll
            for (int mi = 0; mi < 2; ++mi)
#pragma unroll
                for (int j = 0; j < 8; ++j)
                    s[mi][j] = MFMA16(qa[mi][kk], bfr[j], s[mi][j]);
        }
        // blend + write + online stats
#pragma unroll
        for (int mi = 0; mi < 2; ++mi) {
#pragma unroll
            for (int j = 0; j < 8; ++j) {
                const int kcol = kt * 128 + j * 16 + (lane & 15);
                const int qb_ = q0 + mi * 16 + ((lane >> 4) << 2);
#pragma unroll
                for (int r = 0; r < 4; ++r) {
                    const size_t idx = ((size_t)(bh * 1024 + qb_ + r)) * 1024 + kcol;
                    const float bl = g * prev[idx] + og * s[mi][j][r];
                    scoresOut[idx] = bl;
                    s[mi][j][r] = bl;
                }
            }
#pragma unroll
            for (int r = 0; r < 4; ++r) {
                const int len = lenv[mi][r];
                float vm = -1e30f;
#pragma unroll
                for (int j = 0; j < 8; ++j) {
                    const int kcol = kt * 128 + j * 16 + (lane & 15);
                    const float vv = (kcol < len) ? s[mi][j][r] * 0.125f : -1e30f;
                    vm = fmaxf(vm, vv);
                }
                vm = fmaxf(vm, __shfl_xor(vm, 1));
                vm = fmaxf(vm, __shfl_xor(vm, 2));
                vm = fmaxf(vm, __shfl_xor(vm, 4));
                vm = fmaxf(vm, __shfl_xor(vm, 8));
                const float mnew = fmaxf(mrun[mi][r], vm);
                float es = 0.f;
#pragma unroll
                for (int j = 0; j < 8; ++j) {
                    const int kcol = kt * 128 + j * 16 + (lane & 15);
                    if (kcol < len) es += __expf(s[mi][j][r] * 0.125f - mnew);
                }
                es += __shfl_xor(es, 1);
                es += __shfl_xor(es, 2);
                es += __shfl_xor(es, 4);
                es += __shfl_xor(es, 8);
                lrun[mi][r] = lrun[mi][r] * __expf(mrun[mi][r] - mnew) + es;
                mrun[mi][r] = mnew;
            }
        }
        __syncthreads();
    }
    if ((lane & 15) == 0) {
#pragma unroll
        for (int mi = 0; mi < 2; ++mi)
#pragma unroll
            for (int r = 0; r < 4; ++r) {
                const int q = q0 + mi * 16 + ((lane >> 4) << 2) + r;
                rowMax[bh * 1024 + q] = mrun[mi][r];
                rowSum[bh * 1024 + q] = lrun[mi][r];
            }
    }
}

// ---------------------------------------------------------------- P@V
// Reads blended scores back from d_out, P = mask ? exp(s/8 - m)/l : 0 (bf16),
// O = P @ Vt^T via MFMA; writes att in merged [B*L, HID] bf16 layout.
__global__ __launch_bounds__(256, 2) void attn_pv(
    const float* scoresOut, const bf16_t* Vt,
    const int* mask, const float* rowMax, const float* rowSum,
    bf16_t* att) {
    __shared__ __align__(1024) char sm[16384];
    const int tid = threadIdx.x, lane = tid & 63, w = tid >> 6;
    const int bh = blockIdx.y;
    const int q0 = blockIdx.x * 128 + w * 32;

    float mq[2], il[2];
    int len[2];
#pragma unroll
    for (int mi = 0; mi < 2; ++mi) {
        const int q = q0 + mi * 16 + (lane & 15);  // A-layout row
        mq[mi] = rowMax[bh * 1024 + q];
        il[mi] = 1.f / rowSum[bh * 1024 + q];
        len[mi] = mask[(bh & 3) * 1024 + q];
    }

    f32x4 acc[2][4] = {};
    const char* Vb = (const char*)Vt + (size_t)bh * 131072;  // 64*1024*2B
    for (int kt = 0; kt < 8; ++kt) {
        stage16k<8>(Vb + kt * 256, sm, 2048, tid);  // 64 rows x 256B (tile of k)
        __syncthreads();
#pragma unroll
        for (int kk = 0; kk < 4; ++kk) {
            bf16x8 pa[2];
#pragma unroll
            for (int mi = 0; mi < 2; ++mi) {
                const int q = q0 + mi * 16 + (lane & 15);
                const int kbase = kt * 128 + kk * 32 + (lane >> 4) * 8;
                const float* sp = scoresOut + ((size_t)(bh * 1024 + q)) * 1024 + kbase;
                f32x4 v0 = *(const f32x4*)sp;
                f32x4 v1 = *(const f32x4*)(sp + 4);
                bf16x8 p;
#pragma unroll
                for (int e = 0; e < 8; ++e) {
                    const float vv = (e < 4) ? v0[e] : v1[e - 4];
                    const float pe = (kbase + e < len[mi]) ? __expf(vv * 0.125f - mq[mi]) * il[mi] : 0.f;
                    p[e] = (bf16_t)pe;
                }
                pa[mi] = p;
            }
            bf16x8 vb[4];
#pragma unroll
            for (int ni = 0; ni < 4; ++ni)
                vb[ni] = lds_frag<8>(sm, ni * 16 + (lane & 15), kk * 64 + (lane >> 4) * 16);
#pragma unroll
            for (int mi = 0; mi < 2; ++mi)
#pragma unroll
                for (int ni = 0; ni < 4; ++ni)
                    acc[mi][ni] = MFMA16(pa[mi], vb[ni], acc[mi][ni]);
        }
        __syncthreads();
    }

    const int b = bh >> 4, h = bh & 15;
#pragma unroll
    for (int mi = 0; mi < 2; ++mi)
#pragma unroll
        for (int ni = 0; ni < 4; ++ni) {
            const int d = ni * 16 + (lane & 15);
            const int qb_ = q0 + mi * 16 + ((lane >> 4) << 2);
#pragma unroll
            for (int r = 0; r < 4; ++r)
                att[((size_t)(b * 1024 + qb_ + r)) * 1024 + h * 64 + d] = (bf16_t)acc[mi][ni][r];
        }
}

// ---------------------------------------------------------------- launch
extern "C" void kernel_launch(void* const* d_in, const int* in_sizes, int n_in,
                              void* d_out, int out_size, void* d_ws, size_t ws_size,
                              hipStream_t stream) {
    (void)in_sizes; (void)n_in; (void)out_size; (void)ws_size;
    const float* q    = (const float*)d_in[0];
    const float* k    = (const float*)d_in[1];
    const float* v    = (const float*)d_in[2];
    const float* prev = (const float*)d_in[3];
    const int*   mask = (const int*)d_in[4];
    const float* Wq_w = (const float*)d_in[5];
    const float* Wq_b = (const float*)d_in[6];
    const float* Wk_w = (const float*)d_in[7];
    const float* Wk_b = (const float*)d_in[8];
    const float* Wv_w = (const float*)d_in[9];
    const float* Wv_b = (const float*)d_in[10];
    const float* Wo_w = (const float*)d_in[11];
    const float* Wo_b = (const float*)d_in[12];
    const float* gat  = (const float*)d_in[13];

    float* outp   = (float*)d_out;
    float* scores = outp + 4194304;  // [64,1024,1024]

    char* ws = (char*)d_ws;
    bf16_t* qb  = (bf16_t*)(ws + 0);
    bf16_t* kb  = (bf16_t*)(ws + 8388608);
    bf16_t* vb  = (bf16_t*)(ws + 16777216);
    bf16_t* wqb = (bf16_t*)(ws + 25165824);
    bf16_t* wkb = (bf16_t*)(ws + 27262976);
    bf16_t* wvb = (bf16_t*)(ws + 29360128);
    bf16_t* wob = (bf16_t*)(ws + 31457280);
    bf16_t* Qs  = (bf16_t*)(ws + 33554432);
    bf16_t* Ks  = (bf16_t*)(ws + 41943040);
    bf16_t* Vt  = (bf16_t*)(ws + 50331648);
    bf16_t* att = (bf16_t*)(ws + 58720256);
    float* rowMax = (float*)(ws + 67108864);
    float* rowSum = (float*)(ws + 67371008);
    // total ws use: ~64.6 MB

    pack_bf16<<<dim3(2048, 7), 256, 0, stream>>>(q, k, v, Wq_w, Wk_w, Wv_w, Wo_w,
                                                 qb, kb, vb, wqb, wkb, wvb, wob);
    gemm_nt<0><<<dim3(8, 32, 3), 256, 0, stream>>>(qb, kb, vb, wqb, wkb, wvb,
                                                   Wq_b, Wk_b, Wv_b, Qs, Ks, Vt, nullptr);
    attn_scores<<<dim3(8, 64), 256, 0, stream>>>(Qs, Ks, prev, mask, gat,
                                                 scores, rowMax, rowSum);
    attn_pv<<<dim3(8, 64), 256, 0, stream>>>(scores, Vt, mask, rowMax, rowSum, att);
    gemm_nt<1><<<dim3(8, 32, 1), 256, 0, stream>>>(att, nullptr, nullptr, wob, nullptr, nullptr,
                                                   Wo_b, nullptr, nullptr,
                                                   nullptr, nullptr, nullptr, outp);
}

// Round 3
// 744.957 us; speedup vs baseline: 1.1980x; 1.1980x over previous
//
#include <hip/hip_runtime.h>
#include <hip/hip_bf16.h>
#include <stdint.h>

#define AS1 __attribute__((address_space(1)))
#define AS3 __attribute__((address_space(3)))

typedef __bf16 bf16_t;
typedef bf16_t bf16x8 __attribute__((ext_vector_type(8)));
typedef float f32x4 __attribute__((ext_vector_type(4)));
typedef unsigned short u16;
typedef u16 u16x4 __attribute__((ext_vector_type(4)));

#define MFMA16(a, b, c) __builtin_amdgcn_mfma_f32_16x16x32_bf16(a, b, c, 0, 0, 0)

static __device__ __forceinline__ void gload_lds16(const void* g, void* l) {
    __builtin_amdgcn_global_load_lds((const AS1 void*)g, (AS3 void*)l, 16, 0, 0);
}

// Stage 16KB tile into LDS with XOR swizzle ((row&7)<<4) applied on the GLOBAL
// source address (global_load_lds writes LDS linearly: wave base + lane*16).
template <int ROW_SHIFT>
static __device__ __forceinline__ void stage16k(const char* g, char* lds, int gstride, int tid) {
    const int lane = tid & 63, w = tid >> 6;
#pragma unroll
    for (int i = 0; i < 4; ++i) {
        int chunk = w + i * 4;  // wave-uniform
        int p = chunk * 1024 + lane * 16;
        int row = p >> ROW_SHIFT;
        int col = (p & ((1 << ROW_SHIFT) - 1)) ^ ((row & 7) << 4);
        gload_lds16(g + row * gstride + col, lds + chunk * 1024);
    }
}

template <int ROW_SHIFT>
static __device__ __forceinline__ bf16x8 lds_frag(const char* lds, int row, int colb) {
    int off = (row << ROW_SHIFT) + (colb ^ ((row & 7) << 4));
    return *(const bf16x8*)(lds + off);
}

// ---------------------------------------------------------------- pack f32->bf16
__global__ __launch_bounds__(256) void pack_bf16(
    const float* q, const float* k, const float* v,
    const float* wq, const float* wk, const float* wv, const float* wo,
    bf16_t* qb, bf16_t* kb, bf16_t* vb,
    bf16_t* wqb, bf16_t* wkb, bf16_t* wvb, bf16_t* wob) {
    const float* src; bf16_t* dst; int n;
    switch (blockIdx.y) {
        case 0: src = q;  dst = qb;  n = 4194304; break;
        case 1: src = k;  dst = kb;  n = 4194304; break;
        case 2: src = v;  dst = vb;  n = 4194304; break;
        case 3: src = wq; dst = wqb; n = 1048576; break;
        case 4: src = wk; dst = wkb; n = 1048576; break;
        case 5: src = wv; dst = wvb; n = 1048576; break;
        default: src = wo; dst = wob; n = 1048576; break;
    }
    int i = (blockIdx.x * 256 + threadIdx.x) * 8;
    if (i >= n) return;
    f32x4 v0 = *(const f32x4*)(src + i);
    f32x4 v1 = *(const f32x4*)(src + i + 4);
    bf16x8 o;
#pragma unroll
    for (int e = 0; e < 4; ++e) o[e] = (bf16_t)v0[e];
#pragma unroll
    for (int e = 0; e < 4; ++e) o[e + 4] = (bf16_t)v1[e];
    *(bf16x8*)(dst + i) = o;
}

// ---------------------------------------------------------------- NT GEMM (bf16 MFMA)
// C[M=4096, N=1024] = A[M,K=1024] * B[N,K]^T + bias
template <int MODE>
__global__ __launch_bounds__(256, 2) void gemm_nt(
    const bf16_t* A0, const bf16_t* A1, const bf16_t* A2,
    const bf16_t* B0, const bf16_t* B1, const bf16_t* B2,
    const float* bias0, const float* bias1, const float* bias2,
    bf16_t* Qs, bf16_t* Ks, bf16_t* Vt, float* outF) {
    __shared__ __align__(1024) char sm[32768];
    const int tid = threadIdx.x, lane = tid & 63, w = tid >> 6;
    const int wr = w >> 1, wc = w & 1;
    const int m0 = blockIdx.y * 128, n0 = blockIdx.x * 128;
    const int z = (MODE == 0) ? blockIdx.z : 0;

    const bf16_t* A; const bf16_t* Bw; const float* bias;
    if (MODE == 0) {
        A    = (z == 0) ? A0 : (z == 1) ? A1 : A2;
        Bw   = (z == 0) ? B0 : (z == 1) ? B1 : B2;
        bias = (z == 0) ? bias0 : (z == 1) ? bias1 : bias2;
    } else { A = A0; Bw = B0; bias = bias0; }

    const char* Ab = (const char*)A + (size_t)m0 * 2048;
    const char* Bb = (const char*)Bw + (size_t)n0 * 2048;

    f32x4 acc[4][4] = {};
    for (int k0 = 0; k0 < 1024; k0 += 64) {
        stage16k<7>(Ab + k0 * 2, sm, 2048, tid);
        stage16k<7>(Bb + k0 * 2, sm + 16384, 2048, tid);
        __syncthreads();
#pragma unroll
        for (int kk = 0; kk < 2; ++kk) {
            bf16x8 af[4], bfr[4];
#pragma unroll
            for (int i = 0; i < 4; ++i)
                af[i] = lds_frag<7>(sm, wr * 64 + i * 16 + (lane & 15), kk * 64 + (lane >> 4) * 16);
#pragma unroll
            for (int j = 0; j < 4; ++j)
                bfr[j] = lds_frag<7>(sm + 16384, wc * 64 + j * 16 + (lane & 15), kk * 64 + (lane >> 4) * 16);
#pragma unroll
            for (int i = 0; i < 4; ++i)
#pragma unroll
                for (int j = 0; j < 4; ++j)
                    acc[i][j] = MFMA16(af[i], bfr[j], acc[i][j]);
        }
        __syncthreads();
    }

#pragma unroll
    for (int i = 0; i < 4; ++i) {
#pragma unroll
        for (int j = 0; j < 4; ++j) {
            const int mb = m0 + wr * 64 + i * 16 + ((lane >> 4) << 2);
            const int n = n0 + wc * 64 + j * 16 + (lane & 15);
            const float bv = bias[n];
            if (MODE == 1) {
#pragma unroll
                for (int r = 0; r < 4; ++r)
                    outF[(size_t)(mb + r) * 1024 + n] = acc[i][j][r] + bv;
            } else if (z == 2) {
                const int b = mb >> 10, l = mb & 1023;
                const int h = n >> 6, d = n & 63;
                u16x4 pk;
#pragma unroll
                for (int r = 0; r < 4; ++r) {
                    bf16_t x = (bf16_t)(acc[i][j][r] + bv);
                    pk[r] = __builtin_bit_cast(u16, x);
                }
                *(u16x4*)&Vt[((size_t)((b * 16 + h) * 64 + d)) * 1024 + l] = pk;
            } else {
                bf16_t* dst = (z == 0) ? Qs : Ks;
                const int h = n >> 6, d = n & 63;
#pragma unroll
                for (int r = 0; r < 4; ++r) {
                    const int m = mb + r, b = m >> 10, l = m & 1023;
                    dst[((size_t)((b * 16 + h) * 1024 + l)) * 64 + d] = (bf16_t)(acc[i][j][r] + bv);
                }
            }
        }
    }
}

// ---------------------------------------------------------------- scores + stats (v2)
// Barrier-free: no LDS. K fragments load directly from global (L2-resident:
// 128KB/bh shared by 16 blocks). prev tile prefetched into registers before
// the MFMA block so HBM latency hides under compute. Grid (16,64): 64 q-rows
// per block, 4 waves x 16 rows.
__global__ __launch_bounds__(256) void attn_scores(
    const bf16_t* Qs, const bf16_t* Ks,
    const float* prev, const int* mask, const float* gatp,
    float* scoresOut, float* rowMax, float* rowSum) {
    const int tid = threadIdx.x, lane = tid & 63, w = tid >> 6;
    const int bh = blockIdx.y;
    const int q0 = blockIdx.x * 64 + w * 16;
    const float gv = gatp[0];
    const float g = 1.f / (1.f + __expf(-gv));
    const float og = 1.f - g;

    bf16x8 qa[2];
#pragma unroll
    for (int kk = 0; kk < 2; ++kk)
        qa[kk] = *(const bf16x8*)(Qs + ((size_t)(bh * 1024 + q0 + (lane & 15))) * 64 + kk * 32 + (lane >> 4) * 8);

    const int rq = q0 + ((lane >> 4) << 2);  // C-layout row base for this lane
    int len[4]; float mrun[4], lrun[4];
#pragma unroll
    for (int r = 0; r < 4; ++r) {
        len[r] = mask[(bh & 3) * 1024 + rq + r];
        mrun[r] = -1e30f;
        lrun[r] = 0.f;
    }

    const bf16_t* Kb = Ks + (size_t)bh * 65536;
    const float* prow = prev + ((size_t)(bh * 1024 + rq)) * 1024;
    float* srow = scoresOut + ((size_t)(bh * 1024 + rq)) * 1024;

    for (int kt = 0; kt < 8; ++kt) {
        const int kcb = kt * 128 + (lane & 15);
        // prefetch prev tile (issued before MFMA consumes anything)
        float pf[8][4];
#pragma unroll
        for (int j = 0; j < 8; ++j)
#pragma unroll
            for (int r = 0; r < 4; ++r)
                pf[j][r] = prow[(size_t)r * 1024 + kcb + j * 16];

        f32x4 s[8] = {};
#pragma unroll
        for (int kk = 0; kk < 2; ++kk)
#pragma unroll
            for (int j = 0; j < 8; ++j) {
                bf16x8 bfr = *(const bf16x8*)(Kb + ((size_t)(kt * 128 + j * 16 + (lane & 15))) * 64 + kk * 32 + (lane >> 4) * 8);
                s[j] = MFMA16(qa[kk], bfr, s[j]);
            }

        // blend + store + pre-scale for stats
#pragma unroll
        for (int j = 0; j < 8; ++j)
#pragma unroll
            for (int r = 0; r < 4; ++r) {
                const float bl = g * pf[j][r] + og * s[j][r];
                srow[(size_t)r * 1024 + kcb + j * 16] = bl;
                s[j][r] = bl * 0.125f;
            }

        // online masked stats per row
#pragma unroll
        for (int r = 0; r < 4; ++r) {
            const int ln = len[r];
            float vm = -1e30f;
#pragma unroll
            for (int j = 0; j < 8; ++j)
                vm = fmaxf(vm, (kcb + j * 16 < ln) ? s[j][r] : -1e30f);
            vm = fmaxf(vm, __shfl_xor(vm, 1));
            vm = fmaxf(vm, __shfl_xor(vm, 2));
            vm = fmaxf(vm, __shfl_xor(vm, 4));
            vm = fmaxf(vm, __shfl_xor(vm, 8));
            const float mnew = fmaxf(mrun[r], vm);
            float es = 0.f;
#pragma unroll
            for (int j = 0; j < 8; ++j)
                es += (kcb + j * 16 < ln) ? __expf(s[j][r] - mnew) : 0.f;
            es += __shfl_xor(es, 1);
            es += __shfl_xor(es, 2);
            es += __shfl_xor(es, 4);
            es += __shfl_xor(es, 8);
            lrun[r] = lrun[r] * __expf(mrun[r] - mnew) + es;
            mrun[r] = mnew;
        }
    }
    if ((lane & 15) == 0) {
#pragma unroll
        for (int r = 0; r < 4; ++r) {
            rowMax[bh * 1024 + rq + r] = mrun[r];
            rowSum[bh * 1024 + rq + r] = lrun[r];
        }
    }
}

// ---------------------------------------------------------------- P@V (v2)
// Barrier-free streaming: scores re-read vectorized f32x4 in A-frag layout,
// V fragments direct from global (L2-resident). Grid (16,64).
__global__ __launch_bounds__(256) void attn_pv(
    const float* scoresOut, const bf16_t* Vt,
    const int* mask, const float* rowMax, const float* rowSum,
    bf16_t* att) {
    const int tid = threadIdx.x, lane = tid & 63, w = tid >> 6;
    const int bh = blockIdx.y;
    const int q0 = blockIdx.x * 64 + w * 16;
    const int qrow = q0 + (lane & 15);
    const float mq = rowMax[bh * 1024 + qrow];
    const float il = 1.f / rowSum[bh * 1024 + qrow];
    const int len = mask[(bh & 3) * 1024 + qrow];

    const float* srow = scoresOut + ((size_t)(bh * 1024 + qrow)) * 1024;
    const bf16_t* Vb = Vt + (size_t)bh * 65536;

    f32x4 acc[4] = {};
    for (int kt = 0; kt < 8; ++kt) {
        const int kb0 = kt * 128 + (lane >> 4) * 8;
        f32x4 sv[4][2];
#pragma unroll
        for (int kk = 0; kk < 4; ++kk) {
            sv[kk][0] = *(const f32x4*)(srow + kb0 + kk * 32);
            sv[kk][1] = *(const f32x4*)(srow + kb0 + kk * 32 + 4);
        }
#pragma unroll
        for (int kk = 0; kk < 4; ++kk) {
            bf16x8 pa;
#pragma unroll
            for (int e = 0; e < 8; ++e) {
                const float vv = (e < 4) ? sv[kk][0][e] : sv[kk][1][e - 4];
                pa[e] = (bf16_t)((kb0 + kk * 32 + e < len) ? __expf(vv * 0.125f - mq) * il : 0.f);
            }
#pragma unroll
            for (int ni = 0; ni < 4; ++ni) {
                bf16x8 vb = *(const bf16x8*)(Vb + ((size_t)(ni * 16 + (lane & 15))) * 1024 + kt * 128 + kk * 32 + (lane >> 4) * 8);
                acc[ni] = MFMA16(pa, vb, acc[ni]);
            }
        }
    }
    const int b = bh >> 4, h = bh & 15;
    const int rq = q0 + ((lane >> 4) << 2);
#pragma unroll
    for (int ni = 0; ni < 4; ++ni) {
        const int d = ni * 16 + (lane & 15);
#pragma unroll
        for (int r = 0; r < 4; ++r)
            att[((size_t)(b * 1024 + rq + r)) * 1024 + h * 64 + d] = (bf16_t)acc[ni][r];
    }
}

// ---------------------------------------------------------------- launch
extern "C" void kernel_launch(void* const* d_in, const int* in_sizes, int n_in,
                              void* d_out, int out_size, void* d_ws, size_t ws_size,
                              hipStream_t stream) {
    (void)in_sizes; (void)n_in; (void)out_size; (void)ws_size;
    const float* q    = (const float*)d_in[0];
    const float* k    = (const float*)d_in[1];
    const float* v    = (const float*)d_in[2];
    const float* prev = (const float*)d_in[3];
    const int*   mask = (const int*)d_in[4];
    const float* Wq_w = (const float*)d_in[5];
    const float* Wq_b = (const float*)d_in[6];
    const float* Wk_w = (const float*)d_in[7];
    const float* Wk_b = (const float*)d_in[8];
    const float* Wv_w = (const float*)d_in[9];
    const float* Wv_b = (const float*)d_in[10];
    const float* Wo_w = (const float*)d_in[11];
    const float* Wo_b = (const float*)d_in[12];
    const float* gat  = (const float*)d_in[13];

    float* outp   = (float*)d_out;
    float* scores = outp + 4194304;  // [64,1024,1024]

    char* ws = (char*)d_ws;
    bf16_t* qb  = (bf16_t*)(ws + 0);
    bf16_t* kb  = (bf16_t*)(ws + 8388608);
    bf16_t* vb  = (bf16_t*)(ws + 16777216);
    bf16_t* wqb = (bf16_t*)(ws + 25165824);
    bf16_t* wkb = (bf16_t*)(ws + 27262976);
    bf16_t* wvb = (bf16_t*)(ws + 29360128);
    bf16_t* wob = (bf16_t*)(ws + 31457280);
    bf16_t* Qs  = (bf16_t*)(ws + 33554432);
    bf16_t* Ks  = (bf16_t*)(ws + 41943040);
    bf16_t* Vt  = (bf16_t*)(ws + 50331648);
    bf16_t* att = (bf16_t*)(ws + 58720256);
    float* rowMax = (float*)(ws + 67108864);
    float* rowSum = (float*)(ws + 67371008);

    pack_bf16<<<dim3(2048, 7), 256, 0, stream>>>(q, k, v, Wq_w, Wk_w, Wv_w, Wo_w,
                                                 qb, kb, vb, wqb, wkb, wvb, wob);
    gemm_nt<0><<<dim3(8, 32, 3), 256, 0, stream>>>(qb, kb, vb, wqb, wkb, wvb,
                                                   Wq_b, Wk_b, Wv_b, Qs, Ks, Vt, nullptr);
    attn_scores<<<dim3(16, 64), 256, 0, stream>>>(Qs, Ks, prev, mask, gat,
                                                  scores, rowMax, rowSum);
    attn_pv<<<dim3(16, 64), 256, 0, stream>>>(scores, Vt, mask, rowMax, rowSum, att);
    gemm_nt<1><<<dim3(8, 32, 1), 256, 0, stream>>>(att, nullptr, nullptr, wob, nullptr, nullptr,
                                                   Wo_b, nullptr, nullptr,
                                                   nullptr, nullptr, nullptr, outp);
}

// Round 7
// 682.816 us; speedup vs baseline: 1.3070x; 1.0910x over previous
//
#include <hip/hip_runtime.h>
#include <hip/hip_bf16.h>
#include <stdint.h>

#define AS1 __attribute__((address_space(1)))
#define AS3 __attribute__((address_space(3)))

typedef __bf16 bf16_t;
typedef bf16_t bf16x8 __attribute__((ext_vector_type(8)));
typedef bf16_t bf16x4 __attribute__((ext_vector_type(4)));
typedef float f32x4 __attribute__((ext_vector_type(4)));
typedef unsigned short u16;
typedef u16 u16x4 __attribute__((ext_vector_type(4)));

#define MFMA16(a, b, c) __builtin_amdgcn_mfma_f32_16x16x32_bf16(a, b, c, 0, 0, 0)

static __device__ __forceinline__ void gload_lds16(const void* g, void* l) {
    __builtin_amdgcn_global_load_lds((const AS1 void*)g, (AS3 void*)l, 16, 0, 0);
}

// Stage 16KB tile into LDS with XOR swizzle ((row&7)<<4) applied on the GLOBAL
// source address (global_load_lds writes LDS linearly: wave base + lane*16).
template <int ROW_SHIFT>
static __device__ __forceinline__ void stage16k(const char* g, char* lds, int gstride, int tid) {
    const int lane = tid & 63, w = tid >> 6;
#pragma unroll
    for (int i = 0; i < 4; ++i) {
        int chunk = w + i * 4;  // wave-uniform
        int p = chunk * 1024 + lane * 16;
        int row = p >> ROW_SHIFT;
        int col = (p & ((1 << ROW_SHIFT) - 1)) ^ ((row & 7) << 4);
        gload_lds16(g + row * gstride + col, lds + chunk * 1024);
    }
}

template <int ROW_SHIFT>
static __device__ __forceinline__ bf16x8 lds_frag(const char* lds, int row, int colb) {
    int off = (row << ROW_SHIFT) + (colb ^ ((row & 7) << 4));
    return *(const bf16x8*)(lds + off);
}

// ---------------------------------------------------------------- pack f32->bf16
__global__ __launch_bounds__(256) void pack_bf16(
    const float* q, const float* k, const float* v,
    const float* wq, const float* wk, const float* wv, const float* wo,
    bf16_t* qb, bf16_t* kb, bf16_t* vb,
    bf16_t* wqb, bf16_t* wkb, bf16_t* wvb, bf16_t* wob) {
    const float* src; bf16_t* dst; int n;
    switch (blockIdx.y) {
        case 0: src = q;  dst = qb;  n = 4194304; break;
        case 1: src = k;  dst = kb;  n = 4194304; break;
        case 2: src = v;  dst = vb;  n = 4194304; break;
        case 3: src = wq; dst = wqb; n = 1048576; break;
        case 4: src = wk; dst = wkb; n = 1048576; break;
        case 5: src = wv; dst = wvb; n = 1048576; break;
        default: src = wo; dst = wob; n = 1048576; break;
    }
    int i = (blockIdx.x * 256 + threadIdx.x) * 8;
    if (i >= n) return;
    f32x4 v0 = *(const f32x4*)(src + i);
    f32x4 v1 = *(const f32x4*)(src + i + 4);
    bf16x8 o;
#pragma unroll
    for (int e = 0; e < 4; ++e) o[e] = (bf16_t)v0[e];
#pragma unroll
    for (int e = 0; e < 4; ++e) o[e + 4] = (bf16_t)v1[e];
    *(bf16x8*)(dst + i) = o;
}

// ---------------------------------------------------------------- NT GEMM (bf16 MFMA)
// C[M=4096, N=1024] = A[M,K=1024] * B[N,K]^T + bias
template <int MODE>
__global__ __launch_bounds__(256, 2) void gemm_nt(
    const bf16_t* A0, const bf16_t* A1, const bf16_t* A2,
    const bf16_t* B0, const bf16_t* B1, const bf16_t* B2,
    const float* bias0, const float* bias1, const float* bias2,
    bf16_t* Qs, bf16_t* Ks, bf16_t* Vt, float* outF) {
    __shared__ __align__(1024) char sm[32768];
    const int tid = threadIdx.x, lane = tid & 63, w = tid >> 6;
    const int wr = w >> 1, wc = w & 1;
    const int m0 = blockIdx.y * 128, n0 = blockIdx.x * 128;
    const int z = (MODE == 0) ? blockIdx.z : 0;

    const bf16_t* A; const bf16_t* Bw; const float* bias;
    if (MODE == 0) {
        A    = (z == 0) ? A0 : (z == 1) ? A1 : A2;
        Bw   = (z == 0) ? B0 : (z == 1) ? B1 : B2;
        bias = (z == 0) ? bias0 : (z == 1) ? bias1 : bias2;
    } else { A = A0; Bw = B0; bias = bias0; }

    const char* Ab = (const char*)A + (size_t)m0 * 2048;
    const char* Bb = (const char*)Bw + (size_t)n0 * 2048;

    f32x4 acc[4][4] = {};
    for (int k0 = 0; k0 < 1024; k0 += 64) {
        stage16k<7>(Ab + k0 * 2, sm, 2048, tid);
        stage16k<7>(Bb + k0 * 2, sm + 16384, 2048, tid);
        __syncthreads();
#pragma unroll
        for (int kk = 0; kk < 2; ++kk) {
            bf16x8 af[4], bfr[4];
#pragma unroll
            for (int i = 0; i < 4; ++i)
                af[i] = lds_frag<7>(sm, wr * 64 + i * 16 + (lane & 15), kk * 64 + (lane >> 4) * 16);
#pragma unroll
            for (int j = 0; j < 4; ++j)
                bfr[j] = lds_frag<7>(sm + 16384, wc * 64 + j * 16 + (lane & 15), kk * 64 + (lane >> 4) * 16);
#pragma unroll
            for (int i = 0; i < 4; ++i)
#pragma unroll
                for (int j = 0; j < 4; ++j)
                    acc[i][j] = MFMA16(af[i], bfr[j], acc[i][j]);
        }
        __syncthreads();
    }

#pragma unroll
    for (int i = 0; i < 4; ++i) {
#pragma unroll
        for (int j = 0; j < 4; ++j) {
            const int mb = m0 + wr * 64 + i * 16 + ((lane >> 4) << 2);
            const int n = n0 + wc * 64 + j * 16 + (lane & 15);
            const float bv = bias[n];
            if (MODE == 1) {
#pragma unroll
                for (int r = 0; r < 4; ++r)
                    outF[(size_t)(mb + r) * 1024 + n] = acc[i][j][r] + bv;
            } else if (z == 2) {
                const int b = mb >> 10, l = mb & 1023;
                const int h = n >> 6, d = n & 63;
                u16x4 pk;
#pragma unroll
                for (int r = 0; r < 4; ++r) {
                    bf16_t x = (bf16_t)(acc[i][j][r] + bv);
                    pk[r] = __builtin_bit_cast(u16, x);
                }
                *(u16x4*)&Vt[((size_t)((b * 16 + h) * 64 + d)) * 1024 + l] = pk;
            } else {
                bf16_t* dst = (z == 0) ? Qs : Ks;
                const int h = n >> 6, d = n & 63;
#pragma unroll
                for (int r = 0; r < 4; ++r) {
                    const int m = mb + r, b = m >> 10, l = m & 1023;
                    dst[((size_t)((b * 16 + h) * 1024 + l)) * 64 + d] = (bf16_t)(acc[i][j][r] + bv);
                }
            }
        }
    }
}

// ---------------------------------------------------------------- fused scores + softmax + PV
// Swapped QK^T: S^T = mfma(K, Q) puts q in C-layout columns (lane&15), k in rows
// ((lane>>4)*4+r). prev/scores rows are then lane-local -> f32x4 loads/stores.
// Online softmax per q (in-lane reduce + 2 shfl_xor); P repacked to MFMA A-frag
// layout via per-wave private LDS (no barriers, same-wave ds ordering + lgkmcnt).
// O = P@Vt accumulated with flash-style rescale. Grid (16, 64), 4 waves/block.
__global__ __launch_bounds__(256) void attn_fused(
    const bf16_t* Qs, const bf16_t* Ks, const bf16_t* Vt,
    const float* prev, const int* mask, const float* gatp,
    float* scoresOut, bf16_t* att) {
    __shared__ __align__(1024) char psm[16384];
    const int tid = threadIdx.x, lane = tid & 63, w = tid >> 6;
    char* myP = psm + w * 4096;  // 16 rows x 256B, wave-private
    const int bh = blockIdx.y;
    const int q0 = blockIdx.x * 64 + w * 16;
    const int qc = lane & 15;   // this lane's q column (S^T layout)
    const int gq = lane >> 4;   // lane group
    const float gate = 1.f / (1.f + __expf(-gatp[0]));
    const float og = 1.f - gate;

    // Q as MFMA B-operand: lane&15 = q, contraction d = kk*32 + gq*8 + e
    bf16x8 qa[2];
#pragma unroll
    for (int kk = 0; kk < 2; ++kk)
        qa[kk] = *(const bf16x8*)(Qs + ((size_t)(bh * 1024 + q0 + qc)) * 64 + kk * 32 + gq * 8);

    const int len = mask[(bh & 3) * 1024 + q0 + qc];
    float mrun = -1e30f, lrun = 0.f;
    f32x4 acc[4] = {};  // O: row q0 + gq*4 + r, col d = ni*16 + qc

    const bf16_t* Kb = Ks + (size_t)bh * 65536;
    const bf16_t* Vb = Vt + (size_t)bh * 65536;
    const float* prow = prev + ((size_t)(bh * 1024 + q0 + qc)) * 1024;
    float* srow = scoresOut + ((size_t)(bh * 1024 + q0 + qc)) * 1024;

    for (int kt = 0; kt < 8; ++kt) {
        const int kb = kt * 128;
        // prev tile: vectorized, issued early so latency hides under QK^T
        f32x4 pf[8];
#pragma unroll
        for (int j = 0; j < 8; ++j)
            pf[j] = *(const f32x4*)(prow + kb + j * 16 + gq * 4);

        // S^T = K . Q^T  (k rows in C rows, q in C cols)
        f32x4 s[8] = {};
#pragma unroll
        for (int kk = 0; kk < 2; ++kk)
#pragma unroll
            for (int j = 0; j < 8; ++j) {
                bf16x8 ka = *(const bf16x8*)(Kb + ((size_t)(kb + j * 16 + qc)) * 64 + kk * 32 + gq * 8);
                s[j] = MFMA16(ka, qa[kk], s[j]);
            }

        // blend + vectorized store + mask/scale
#pragma unroll
        for (int j = 0; j < 8; ++j) {
            f32x4 bl;
#pragma unroll
            for (int r = 0; r < 4; ++r) bl[r] = gate * pf[j][r] + og * s[j][r];
            *(f32x4*)(srow + kb + j * 16 + gq * 4) = bl;
#pragma unroll
            for (int r = 0; r < 4; ++r)
                s[j][r] = (kb + j * 16 + gq * 4 + r < len) ? bl[r] * 0.125f : -1e30f;
        }

        // online softmax stats for this tile (per q = lane column)
        float vm = -1e30f;
#pragma unroll
        for (int j = 0; j < 8; ++j)
#pragma unroll
            for (int r = 0; r < 4; ++r) vm = fmaxf(vm, s[j][r]);
        vm = fmaxf(vm, __shfl_xor(vm, 16));
        vm = fmaxf(vm, __shfl_xor(vm, 32));
        const float mnew = fmaxf(mrun, vm);

        float ps = 0.f;
#pragma unroll
        for (int j = 0; j < 8; ++j)
#pragma unroll
            for (int r = 0; r < 4; ++r) {
                const float p = __expf(s[j][r] - mnew);  // masked: exp(-1e30-m) -> 0
                s[j][r] = p;
                ps += p;
            }
        ps += __shfl_xor(ps, 16);
        ps += __shfl_xor(ps, 32);
        const float corr = __expf(mrun - mnew);
        lrun = lrun * corr + ps;
        mrun = mnew;

        // rescale O accumulator (per O-row q = gq*4 + r; corr is per q-column)
        float cr[4];
#pragma unroll
        for (int r = 0; r < 4; ++r) cr[r] = __shfl(corr, gq * 4 + r);
#pragma unroll
        for (int ni = 0; ni < 4; ++ni)
#pragma unroll
            for (int r = 0; r < 4; ++r) acc[ni][r] *= cr[r];

        // repack P~ (S^T C-layout) -> row-major [q][k] bf16 in wave-private LDS.
        // write: row qc, bytes [j*32+gq*8, +8)  (k = j*16+gq*4+r), XOR-swizzled.
#pragma unroll
        for (int j = 0; j < 8; ++j) {
            bf16x4 pk;
#pragma unroll
            for (int r = 0; r < 4; ++r) pk[r] = (bf16_t)s[j][r];
            int boff = qc * 256 + j * 32 + gq * 8;
            boff ^= (qc & 7) << 4;
            *(bf16x4*)(myP + boff) = pk;
        }
        asm volatile("s_waitcnt lgkmcnt(0)" ::: "memory");

        // PV: A-frag = 16B row-chunk [q][kk*32+gq*8 ..+7]; B-frag = Vt rows (d)
#pragma unroll
        for (int kk = 0; kk < 4; ++kk) {
            int roff = qc * 256 + kk * 64 + gq * 16;
            roff ^= (qc & 7) << 4;
            const bf16x8 pa = *(const bf16x8*)(myP + roff);
#pragma unroll
            for (int ni = 0; ni < 4; ++ni) {
                bf16x8 vb = *(const bf16x8*)(Vb + ((size_t)(ni * 16 + qc)) * 1024 + kb + kk * 32 + gq * 8);
                acc[ni] = MFMA16(pa, vb, acc[ni]);
            }
        }
        asm volatile("" ::: "memory");  // keep next iter's ds_writes after these reads
    }

    const float il = 1.f / lrun;
    float ir[4];
#pragma unroll
    for (int r = 0; r < 4; ++r) ir[r] = __shfl(il, gq * 4 + r);
    const int b = bh >> 4, h = bh & 15;
#pragma unroll
    for (int ni = 0; ni < 4; ++ni)
#pragma unroll
        for (int r = 0; r < 4; ++r)
            att[((size_t)(b * 1024 + q0 + gq * 4 + r)) * 1024 + h * 64 + ni * 16 + qc] =
                (bf16_t)(acc[ni][r] * ir[r]);
}

// ---------------------------------------------------------------- launch
extern "C" void kernel_launch(void* const* d_in, const int* in_sizes, int n_in,
                              void* d_out, int out_size, void* d_ws, size_t ws_size,
                              hipStream_t stream) {
    (void)in_sizes; (void)n_in; (void)out_size; (void)ws_size;
    const float* q    = (const float*)d_in[0];
    const float* k    = (const float*)d_in[1];
    const float* v    = (const float*)d_in[2];
    const float* prev = (const float*)d_in[3];
    const int*   mask = (const int*)d_in[4];
    const float* Wq_w = (const float*)d_in[5];
    const float* Wq_b = (const float*)d_in[6];
    const float* Wk_w = (const float*)d_in[7];
    const float* Wk_b = (const float*)d_in[8];
    const float* Wv_w = (const float*)d_in[9];
    const float* Wv_b = (const float*)d_in[10];
    const float* Wo_w = (const float*)d_in[11];
    const float* Wo_b = (const float*)d_in[12];
    const float* gat  = (const float*)d_in[13];

    float* outp   = (float*)d_out;
    float* scores = outp + 4194304;  // [64,1024,1024]

    char* ws = (char*)d_ws;
    bf16_t* qb  = (bf16_t*)(ws + 0);
    bf16_t* kb  = (bf16_t*)(ws + 8388608);
    bf16_t* vb  = (bf16_t*)(ws + 16777216);
    bf16_t* wqb = (bf16_t*)(ws + 25165824);
    bf16_t* wkb = (bf16_t*)(ws + 27262976);
    bf16_t* wvb = (bf16_t*)(ws + 29360128);
    bf16_t* wob = (bf16_t*)(ws + 31457280);
    bf16_t* Qs  = (bf16_t*)(ws + 33554432);
    bf16_t* Ks  = (bf16_t*)(ws + 41943040);
    bf16_t* Vt  = (bf16_t*)(ws + 50331648);
    bf16_t* att = (bf16_t*)(ws + 58720256);

    pack_bf16<<<dim3(2048, 7), 256, 0, stream>>>(q, k, v, Wq_w, Wk_w, Wv_w, Wo_w,
                                                 qb, kb, vb, wqb, wkb, wvb, wob);
    gemm_nt<0><<<dim3(8, 32, 3), 256, 0, stream>>>(qb, kb, vb, wqb, wkb, wvb,
                                                   Wq_b, Wk_b, Wv_b, Qs, Ks, Vt, nullptr);
    attn_fused<<<dim3(16, 64), 256, 0, stream>>>(Qs, Ks, Vt, prev, mask, gat,
                                                 scores, att);
    gemm_nt<1><<<dim3(8, 32, 1), 256, 0, stream>>>(att, nullptr, nullptr, wob, nullptr, nullptr,
                                                   Wo_b, nullptr, nullptr,
                                                   nullptr, nullptr, nullptr, outp);
}